// Round 6
// baseline (97.265 us; speedup 1.0000x reference)
//
#include <hip/hip_runtime.h>

// ThinPlateSpline: out = K_query @ rbf_weights + P_query @ poly_coeffs
//   K_ij = r*ln(r), r = ||u_i - c_j|| (d=3)
//   k = sqrt(r2) * 0.5*ln(r2);  0.5 folded into staged weights.
//
// R6: all-rounds evidence says v_sqrt+v_log (~32 cyc/wave each?) are the
// floor. Replace both with full-rate VALU:
//   sqrt: rsqrt bit-hack + 1 Newton (rel err 1.7e-3), sqrt = r2*y
//   ln:   exponent split at sqrt(1/2) via int ops + deg-5 Taylor ln(1+s),
//         s in [-0.293, 0.414], abs err ~8e-4
// Per-pair error ~2e-3 * sqrt(4096) ~ 0.15 << 0.75 threshold.
// Structure: BLK=512 (8 waves = 8 n-splits of same 256 queries, QPT=4),
// LDS broadcast delivery (2 x ds_read_b128 per j per wave, amortized over
// 4 pairs), in-block LDS reduction, atomics only across grid.y=8 (393K).
// grid (64,8) = 512 blocks -> 4 waves/SIMD.

#define BLK 512
#define NS 8            // in-block n-splits (one per wave)
#define QPT 4           // queries per lane
#define QPB 256         // 64 lanes * QPT
#define JCHUNK 512      // j per block
#define JW (JCHUNK / NS)

__global__ __launch_bounds__(BLK) void tps_kernel(
    const float* __restrict__ u,     // (batch, 3)
    const float* __restrict__ cp,    // (n, 3)
    const float* __restrict__ w,     // (n, 3)
    const float* __restrict__ poly,  // (4, 3)
    float* __restrict__ out,         // (batch, 3)
    int batch, int n)
{
    __shared__ float4 s_a[JCHUNK];          // {-2cx, -2cy, -2cz, |c|^2}
    __shared__ float4 s_b[JCHUNK];          // {w/2, 0}
    __shared__ float  s_red[NS][QPB * 3];   // per-wave partials

    const int tid = threadIdx.x;
    const int j0 = blockIdx.y * JCHUNK;

    {   // stage + transform this block's 512-j slice (BLK == JCHUNK)
        const int g = j0 + tid;
        const float cx = cp[g * 3 + 0], cy = cp[g * 3 + 1], cz = cp[g * 3 + 2];
        s_a[tid] = make_float4(-2.f * cx, -2.f * cy, -2.f * cz,
                               fmaf(cx, cx, fmaf(cy, cy, cz * cz)));
        s_b[tid] = make_float4(0.5f * w[g * 3 + 0], 0.5f * w[g * 3 + 1],
                               0.5f * w[g * 3 + 2], 0.f);
    }
    __syncthreads();

    const int lane = tid & 63;
    const int wv   = tid >> 6;    // 0..7 = n-split

    float ux[QPT], uy[QPT], uz[QPT], usq[QPT];
    float ax[QPT], ay[QPT], az[QPT];
#pragma unroll
    for (int k = 0; k < QPT; ++k) {
        const int q  = blockIdx.x * QPB + k * 64 + lane;
        const int ql = q < batch ? q : batch - 1;
        ux[k] = u[ql * 3 + 0];
        uy[k] = u[ql * 3 + 1];
        uz[k] = u[ql * 3 + 2];
        usq[k] = fmaf(ux[k], ux[k], fmaf(uy[k], uy[k], uz[k] * uz[k]));
        ax[k] = ay[k] = az[k] = 0.f;
    }

    if (blockIdx.y == 0 && wv == 0) {  // poly term exactly once per query
#pragma unroll
        for (int k = 0; k < QPT; ++k) {
            ax[k] = poly[0] + ux[k] * poly[3] + uy[k] * poly[6] + uz[k] * poly[9];
            ay[k] = poly[1] + ux[k] * poly[4] + uy[k] * poly[7] + uz[k] * poly[10];
            az[k] = poly[2] + ux[k] * poly[5] + uy[k] * poly[8] + uz[k] * poly[11];
        }
    }

    const int jlo = wv * JW;
#pragma unroll 4
    for (int j = jlo; j < jlo + JW; ++j) {
        const float4 A = s_a[j];   // broadcast (wave-uniform address)
        const float4 B = s_b[j];
#pragma unroll
        for (int k = 0; k < QPT; ++k) {
            float r2 = fmaf(A.x, ux[k],
                       fmaf(A.y, uy[k],
                       fmaf(A.z, uz[k], A.w + usq[k])));
            r2 = fmaxf(r2, 1e-30f);
            const int bi = __float_as_int(r2);

            // sqrt via rsqrt bit-hack + 1 Newton
            float y = __int_as_float(0x5f3759df - (bi >> 1));
            y = y * fmaf(-0.5f * r2, y * y, 1.5f);
            const float sq = r2 * y;               // ~sqrt(r2), rel 1.7e-3

            // ln(r2) = e*ln2 + ln(m), m in [sqrt(1/2), sqrt(2))
            const int   e  = (bi - 0x3f3504f3) >> 23;
            const float m  = __int_as_float(bi - (e << 23));
            const float s  = m - 1.0f;             // in [-0.293, 0.414]
            float t = fmaf(s, 0.2f, -0.25f);
            t = fmaf(s, t, 0.33333334f);
            t = fmaf(s, t, -0.5f);
            t = fmaf(s, t, 1.0f);
            const float g = fmaf((float)e, 0.69314718f, s * t);

            const float kk = sq * g;               // sqrt(r2)*ln(r2)
            ax[k] = fmaf(kk, B.x, ax[k]);
            ay[k] = fmaf(kk, B.y, ay[k]);
            az[k] = fmaf(kk, B.z, az[k]);
        }
    }

    // In-block reduction across the 8 n-split waves.
#pragma unroll
    for (int k = 0; k < QPT; ++k) {
        const int base = (k * 64 + lane) * 3;
        s_red[wv][base + 0] = ax[k];
        s_red[wv][base + 1] = ay[k];
        s_red[wv][base + 2] = az[k];
    }
    __syncthreads();

    for (int v = tid; v < QPB * 3; v += BLK) {
        float s = 0.f;
#pragma unroll
        for (int ww = 0; ww < NS; ++ww) s += s_red[ww][v];
        const size_t o = (size_t)blockIdx.x * (QPB * 3) + v;
        if (o < (size_t)batch * 3) atomicAdd(&out[o], s);
    }
}

extern "C" void kernel_launch(void* const* d_in, const int* in_sizes, int n_in,
                              void* d_out, int out_size, void* d_ws, size_t ws_size,
                              hipStream_t stream) {
    const float* u    = (const float*)d_in[0];  // (batch,3)
    const float* cp   = (const float*)d_in[1];  // (n,3)
    const float* w    = (const float*)d_in[2];  // (n,3)
    const float* poly = (const float*)d_in[3];  // (4,3)
    float* out = (float*)d_out;

    const int batch = in_sizes[0] / 3;  // 16384
    const int n     = in_sizes[1] / 3;  // 4096

    hipMemsetAsync(d_out, 0, (size_t)out_size * sizeof(float), stream);

    dim3 block(BLK);
    dim3 grid(batch / QPB, n / JCHUNK);  // (64, 8)
    tps_kernel<<<grid, block, 0, stream>>>(u, cp, w, poly, out, batch, n);
}

// Round 7
// 80.322 us; speedup vs baseline: 1.2109x; 1.2109x over previous
//
#include <hip/hip_runtime.h>

// ThinPlateSpline: out = K_query @ rbf_weights + P_query @ poly_coeffs
//   K_ij = r*ln(r), r = ||u_i - c_j|| (d=3)
//   r*ln(r) = sqrt(r2) * (0.5*ln2) * log2(r2); C=0.5*ln2 folded into staged w.
//   r2 = usq + |c|^2 - 2 u.c (expanded form; fmax guard for cancellation<=0)
//
// R7: R6 proved hw v_sqrt/v_log (quarter-rate ~8cyc) beat the 28-op software
// version, and that the VALU sat 30% idle at 4 waves/SIMD (grid-limited).
// This round: hw trans + max occupancy. BLK=256 = 4 waves = 4 in-block
// n-splits of the same 128 queries (QPT=2); JCHUNK=256 -> grid (128,16) =
// 2048 blocks = 8 blocks/CU = 32 waves/CU. LDS 14 KB/block (112 KB/CU ok).
// In-block LDS reduction, then coalesced atomics across grid.y=16 (786K
// atomics, coalesced -> ~3 MB HBM, proven cheap in R6).

#define BLK 256
#define NS 4            // waves per block = in-block n-splits
#define QPT 2           // queries per lane
#define QPB 128         // queries per block = 64 * QPT
#define JCHUNK 256      // j per block
#define JW (JCHUNK / NS)

__global__ __launch_bounds__(BLK, 8) void tps_kernel(
    const float* __restrict__ u,     // (batch, 3)
    const float* __restrict__ cp,    // (n, 3)
    const float* __restrict__ w,     // (n, 3)
    const float* __restrict__ poly,  // (4, 3)
    float* __restrict__ out,         // (batch, 3)
    int batch, int n)
{
    __shared__ float4 s_a[JCHUNK];         // {-2cx, -2cy, -2cz, |c|^2}
    __shared__ float4 s_b[JCHUNK];         // {C*w, 0}
    __shared__ float  s_red[NS][QPB * 3];  // per-wave partial sums (6 KB)

    const float C = 0.34657359027997264f;  // 0.5 * ln(2)

    const int tid = threadIdx.x;
    const int j0 = blockIdx.y * JCHUNK;

    {   // stage + transform this block's 256-j slice (BLK == JCHUNK)
        const int g = j0 + tid;
        const float cx = cp[g * 3 + 0], cy = cp[g * 3 + 1], cz = cp[g * 3 + 2];
        s_a[tid] = make_float4(-2.f * cx, -2.f * cy, -2.f * cz,
                               fmaf(cx, cx, fmaf(cy, cy, cz * cz)));
        s_b[tid] = make_float4(C * w[g * 3 + 0], C * w[g * 3 + 1],
                               C * w[g * 3 + 2], 0.f);
    }
    __syncthreads();

    const int lane = tid & 63;
    const int wv   = tid >> 6;    // 0..3 = n-split

    float ux[QPT], uy[QPT], uz[QPT], usq[QPT];
    float ax[QPT], ay[QPT], az[QPT];
#pragma unroll
    for (int k = 0; k < QPT; ++k) {
        const int q = blockIdx.x * QPB + k * 64 + lane;  // always < batch
        ux[k] = u[q * 3 + 0];
        uy[k] = u[q * 3 + 1];
        uz[k] = u[q * 3 + 2];
        usq[k] = fmaf(ux[k], ux[k], fmaf(uy[k], uy[k], uz[k] * uz[k]));
        ax[k] = ay[k] = az[k] = 0.f;
    }

    if (blockIdx.y == 0 && wv == 0) {  // polynomial term exactly once
#pragma unroll
        for (int k = 0; k < QPT; ++k) {
            ax[k] = poly[0] + ux[k] * poly[3] + uy[k] * poly[6] + uz[k] * poly[9];
            ay[k] = poly[1] + ux[k] * poly[4] + uy[k] * poly[7] + uz[k] * poly[10];
            az[k] = poly[2] + ux[k] * poly[5] + uy[k] * poly[8] + uz[k] * poly[11];
        }
    }

    const int jlo = wv * JW;
#pragma unroll 4
    for (int j = jlo; j < jlo + JW; ++j) {
        const float4 A = s_a[j];   // wave-uniform broadcast, ds_read_b128
        const float4 B = s_b[j];
#pragma unroll
        for (int k = 0; k < QPT; ++k) {
            float r2 = fmaf(A.x, ux[k],
                       fmaf(A.y, uy[k],
                       fmaf(A.z, uz[k], A.w + usq[k])));
            r2 = fmaxf(r2, 1e-30f);
            const float kk = __builtin_amdgcn_sqrtf(r2) *
                             __builtin_amdgcn_logf(r2);   // sqrt * log2
            ax[k] = fmaf(kk, B.x, ax[k]);
            ay[k] = fmaf(kk, B.y, ay[k]);
            az[k] = fmaf(kk, B.z, az[k]);
        }
    }

    // In-block reduction across the 4 n-split waves.
#pragma unroll
    for (int k = 0; k < QPT; ++k) {
        const int base = (k * 64 + lane) * 3;
        s_red[wv][base + 0] = ax[k];
        s_red[wv][base + 1] = ay[k];
        s_red[wv][base + 2] = az[k];
    }
    __syncthreads();

    for (int v = tid; v < QPB * 3; v += BLK) {
        float s = s_red[0][v] + s_red[1][v] + s_red[2][v] + s_red[3][v];
        atomicAdd(&out[(size_t)blockIdx.x * (QPB * 3) + v], s);
    }
}

extern "C" void kernel_launch(void* const* d_in, const int* in_sizes, int n_in,
                              void* d_out, int out_size, void* d_ws, size_t ws_size,
                              hipStream_t stream) {
    const float* u    = (const float*)d_in[0];  // (batch,3)
    const float* cp   = (const float*)d_in[1];  // (n,3)
    const float* w    = (const float*)d_in[2];  // (n,3)
    const float* poly = (const float*)d_in[3];  // (4,3)
    float* out = (float*)d_out;

    const int batch = in_sizes[0] / 3;  // 16384
    const int n     = in_sizes[1] / 3;  // 4096

    hipMemsetAsync(d_out, 0, (size_t)out_size * sizeof(float), stream);

    dim3 block(BLK);
    dim3 grid(batch / QPB, n / JCHUNK);  // (128, 16) = 2048 blocks
    tps_kernel<<<grid, block, 0, stream>>>(u, cp, w, poly, out, batch, n);
}